// Round 10
// baseline (2224.261 us; speedup 1.0000x reference)
//
#include <hip/hip_runtime.h>
#include <math.h>

#define D 256
#define V 10000
#define BB 16
#define NN 22
#define CF 400
#define CR 120
#define CA 48
#define CRP 121     // compact rows incl zero slot at 120
#define PADR 5      // LDS row stride (floats) for 4-wide b slices

// ---------------- MLP: 2 rows/block, 512 threads = 2 d-halves x 256 cols ----------------
__global__ __launch_bounds__(512) void k_mlp(const float* __restrict__ nt_emb, const float* __restrict__ W1,
                      const float* __restrict__ b1, const float* __restrict__ resW,
                      const float* __restrict__ resb, const float* __restrict__ Wo,
                      const float* __restrict__ bo, float* __restrict__ split_scores) {
  __shared__ float xs[2][D], hs[2][D], ts[2][D], prt[2][2][D];
  __shared__ float redg[2][4][2];
  int t = threadIdx.x; int c = t & 255; int h = t >> 8;
  int f0 = blockIdx.x * 2;
  xs[h][c] = nt_emb[(size_t)(f0 + h) * D + c];
  __syncthreads();
  int d0 = h * 128;
  float a0 = 0.f, a1 = 0.f;
#pragma unroll 8
  for (int dd = 0; dd < 128; dd++) {
    float wv = W1[(size_t)(d0 + dd) * D + c];
    a0 += xs[0][d0 + dd] * wv; a1 += xs[1][d0 + dd] * wv;
  }
  prt[0][h][c] = a0; prt[1][h][c] = a1;
  __syncthreads();
  if (h == 0) {
    float bv = b1[c];
    hs[0][c] = prt[0][0][c] + prt[0][1][c] + bv;
    hs[1][c] = prt[1][0][c] + prt[1][1][c] + bv;
  }
  __syncthreads();
  for (int il = 0; il < 2; il++) {
    const float* W = resW + (size_t)(il * 2) * D * D;
    a0 = 0.f; a1 = 0.f;
#pragma unroll 8
    for (int dd = 0; dd < 128; dd++) {
      float wv = W[(size_t)(d0 + dd) * D + c];
      a0 += hs[0][d0 + dd] * wv; a1 += hs[1][d0 + dd] * wv;
    }
    prt[0][h][c] = a0; prt[1][h][c] = a1;
    __syncthreads();
    if (h == 0) {
      float bv = resb[(il * 2) * D + c];
      ts[0][c] = fmaxf(prt[0][0][c] + prt[0][1][c] + bv, 0.f);
      ts[1][c] = fmaxf(prt[1][0][c] + prt[1][1][c] + bv, 0.f);
    }
    __syncthreads();
    const float* W2 = resW + (size_t)(il * 2 + 1) * D * D;
    a0 = 0.f; a1 = 0.f;
#pragma unroll 8
    for (int dd = 0; dd < 128; dd++) {
      float wv = W2[(size_t)(d0 + dd) * D + c];
      a0 += ts[0][d0 + dd] * wv; a1 += ts[1][d0 + dd] * wv;
    }
    prt[0][h][c] = a0; prt[1][h][c] = a1;
    __syncthreads();
    if (h == 0) {
      float bv = resb[(il * 2 + 1) * D + c];
      hs[0][c] = fmaxf(prt[0][0][c] + prt[0][1][c] + bv, 0.f) + hs[0][c];
      hs[1][c] = fmaxf(prt[1][0][c] + prt[1][1][c] + bv, 0.f) + hs[1][c];
    }
    __syncthreads();
  }
  float y0 = hs[h][c] * Wo[c * 2 + 0], y1 = hs[h][c] * Wo[c * 2 + 1];
  for (int off = 32; off; off >>= 1) { y0 += __shfl_down(y0, off, 64); y1 += __shfl_down(y1, off, 64); }
  int wq = (t >> 6) & 3;
  if ((t & 63) == 0) { redg[h][wq][0] = y0; redg[h][wq][1] = y1; }
  __syncthreads();
  if (c == 0) {
    float s0 = redg[h][0][0] + redg[h][1][0] + redg[h][2][0] + redg[h][3][0] + bo[0];
    float s1 = redg[h][0][1] + redg[h][1][1] + redg[h][2][1] + redg[h][3][1] + bo[1];
    float m = fmaxf(s0, s1);
    float z = m + __logf(__expf(s0 - m) + __expf(s1 - m));
    split_scores[(f0 + h) * 2 + 0] = s0 - z;
    split_scores[(f0 + h) * 2 + 1] = s1 - z;
  }
}

// ---------------- emission partition: RT=8, 128 thr, 512-col tiles, XCD-swizzled, guarded ----------------
#define RT 8
__global__ __launch_bounds__(128) void k_emit_partial(const float* __restrict__ nt_emb,
                               const float* __restrict__ emit_W,
                               const float* __restrict__ emit_b, float* __restrict__ partial) {
  __shared__ float xs[RT][D];
  __shared__ float ldsw[RT][2];
  int bid = blockIdx.x;
  int xcd = bid & 7;
  int n = bid >> 3;            // 0..149
  int xt = n % 50;             // row group
  int yh = n / 50;             // 0..2
  int y = yh * 8 + xcd;        // col tile; all row-blocks of tile y share bid%8 -> same XCD
  if (y >= 20) return;
  int t = threadIdx.x;
  int f0 = xt * RT;
  int v0 = y * 512 + t * 4;
  for (int idx = t; idx < RT * D; idx += 128) {
    int ri = idx >> 8, d = idx & 255;
    xs[ri][d] = nt_emb[(size_t)(f0 + ri) * D + d];
  }
  __syncthreads();
  float psum[RT];
  for (int ri = 0; ri < RT; ri++) psum[ri] = 0.f;
  if (v0 < V) {                // guard: tile 19 spans 9728..10239 > V
    float acc[RT][4];
#pragma unroll
    for (int ri = 0; ri < RT; ri++)
      for (int j = 0; j < 4; j++) acc[ri][j] = 0.f;
#pragma unroll 2
    for (int d4 = 0; d4 < D / 4; d4++) {
      float4 w0 = *(const float4*)(emit_W + (size_t)(4 * d4 + 0) * V + v0);
      float4 w1 = *(const float4*)(emit_W + (size_t)(4 * d4 + 1) * V + v0);
      float4 w2 = *(const float4*)(emit_W + (size_t)(4 * d4 + 2) * V + v0);
      float4 w3 = *(const float4*)(emit_W + (size_t)(4 * d4 + 3) * V + v0);
#pragma unroll
      for (int ri = 0; ri < RT; ri++) {
        float4 xv = *(const float4*)(&xs[ri][4 * d4]);
        acc[ri][0] += xv.x * w0.x + xv.y * w1.x + xv.z * w2.x + xv.w * w3.x;
        acc[ri][1] += xv.x * w0.y + xv.y * w1.y + xv.z * w2.y + xv.w * w3.y;
        acc[ri][2] += xv.x * w0.z + xv.y * w1.z + xv.z * w2.z + xv.w * w3.z;
        acc[ri][3] += xv.x * w0.w + xv.y * w1.w + xv.z * w2.w + xv.w * w3.w;
      }
    }
    float4 eb = *(const float4*)(emit_b + v0);
#pragma unroll
    for (int ri = 0; ri < RT; ri++)
      psum[ri] = __expf(acc[ri][0] + eb.x) + __expf(acc[ri][1] + eb.y) +
                 __expf(acc[ri][2] + eb.z) + __expf(acc[ri][3] + eb.w);
  }
  int lane = t & 63, wid = t >> 6;
  for (int ri = 0; ri < RT; ri++) {
    float v = psum[ri];
    for (int off = 32; off; off >>= 1) v += __shfl_down(v, off, 64);
    if (lane == 0) ldsw[ri][wid] = v;
  }
  __syncthreads();
  if (t < RT) partial[(f0 + t) * 32 + y] = ldsw[t][0] + ldsw[t][1];
}

// ---------------- rules pack + logZ (block CR does logZ) ----------------
__global__ void k_glgr(const float* __restrict__ rule_W, const float* __restrict__ rule_b,
                       const float* __restrict__ split_scores,
                       const int* __restrict__ lf, const int* __restrict__ rf,
                       const float* __restrict__ partialE, float* __restrict__ logZ,
                       float4* __restrict__ rules) {
  __shared__ float red[128];
  __shared__ float shv[96];
  int r = blockIdx.x;
  int t = threadIdx.x;
  if (r == CR) {
    for (int f = t; f < CF; f += 128) {
      float s = 0.f;
      for (int ct = 0; ct < 20; ct++) s += partialE[f * 32 + ct];
      logZ[f] = __logf(s);
    }
    return;
  }
  float x = (t < 96) ? (rule_W[t * CR + r] + rule_b[t]) : -INFINITY;
  red[t] = x; __syncthreads();
  for (int off = 64; off; off >>= 1) { if (t < off) red[t] = fmaxf(red[t], red[t + off]); __syncthreads(); }
  float m = red[0]; __syncthreads();
  red[t] = (t < 96) ? __expf(x - m) : 0.f; __syncthreads();
  for (int off = 64; off; off >>= 1) { if (t < off) red[t] += red[t + off]; __syncthreads(); }
  float z = m + __logf(red[0]);
  float s0 = split_scores[r * 2 + 0];
  if (t < 96) shv[t] = __expf((x - z) + s0);
  __syncthreads();
  if (t < CA) {
    float4 pk;
    pk.x = shv[t];
    pk.y = shv[CA + t];
    pk.z = __int_as_float(rf[r * CA + t]);
    pk.w = __int_as_float(lf[r * CA + t]);
    rules[r * CA + t] = pk;
  }
}

// ---------------- terminal: ET[n][f][b] = exp(term - bmax), bmax to table ----------------
__global__ __launch_bounds__(512) void k_term(const float* __restrict__ nt_emb,
                       const float* __restrict__ emit_W,
                       const float* __restrict__ emit_b, const int* __restrict__ words,
                       const float* __restrict__ split_scores, const float* __restrict__ logZ,
                       float* __restrict__ ET, float* __restrict__ bmax) {
  __shared__ float vals[CF];
  __shared__ float redw[8];
  __shared__ float mfin;
  int blk = blockIdx.x;
  int b = blk / NN, n = blk % NN;
  int t = threadIdx.x;
  int lane = t & 63, wid = t >> 6;
  int wd = words[b * NN + n];
  float wc0 = emit_W[(size_t)(4 * lane + 0) * V + wd];
  float wc1 = emit_W[(size_t)(4 * lane + 1) * V + wd];
  float wc2 = emit_W[(size_t)(4 * lane + 2) * V + wd];
  float wc3 = emit_W[(size_t)(4 * lane + 3) * V + wd];
  float eb = emit_b[wd];
  float vmax = -INFINITY;
  int fbase = wid * 50;
  for (int k = 0; k < 50; k += 2) {
    int f0 = fbase + k, f1 = f0 + 1;
    float4 xa = *(const float4*)(nt_emb + (size_t)f0 * D + 4 * lane);
    float4 xb = *(const float4*)(nt_emb + (size_t)f1 * D + 4 * lane);
    float va = xa.x * wc0 + xa.y * wc1 + xa.z * wc2 + xa.w * wc3;
    float vb = xb.x * wc0 + xb.y * wc1 + xb.z * wc2 + xb.w * wc3;
    for (int off = 32; off; off >>= 1) {
      va += __shfl_down(va, off, 64);
      vb += __shfl_down(vb, off, 64);
    }
    if (lane == 0) {
      float fa = split_scores[f0 * 2 + 1] + (va + eb) - logZ[f0];
      float fb = split_scores[f1 * 2 + 1] + (vb + eb) - logZ[f1];
      vals[f0] = fa; vals[f1] = fb;
      vmax = fmaxf(vmax, fmaxf(fa, fb));
    }
  }
  if (lane == 0) redw[wid] = vmax;
  __syncthreads();
  if (t == 0) {
    float m = redw[0];
    for (int i2 = 1; i2 < 8; i2++) m = fmaxf(m, redw[i2]);
    mfin = m;
    bmax[(n * NN + n) * BB + b] = m;
  }
  __syncthreads();
  float m = mfin;
  for (int f = t; f < CF; f += 512) ET[((size_t)n * CF + f) * BB + b] = __expf(vals[f] - m);
}

// ---------------- CKY width step: ONE kernel per width, block = (span, b-quartet) ----------------
// 512 threads = 4 k-subgroups x 128 r. All k of the span in one block -> comb is inline.
__global__ __launch_bounds__(512) void k_cky_w(const float4* __restrict__ rules,
                      const float* __restrict__ ET, float* __restrict__ EB,
                      float* __restrict__ bmax, int w) {
  __shared__ float ETL[CF * PADR];      // left diagonal child (k=0), 4 b's
  __shared__ float ETR[CF * PADR];      // right diagonal child (k=wm1-1)
  __shared__ float SLc[4][CRP * PADR];  // compact left slices (chunk of 4 k)
  __shared__ float SRc[4][CRP * PADR];
  __shared__ float4 sred[512];
  __shared__ float sM[21][4];
  __shared__ float Mb4[4];
  __shared__ float msum[4];
  __shared__ float sums[CR][4];
  int t = threadIdx.x;
  int s = blockIdx.x >> 2, bq = blockIdx.x & 3;
  int b0 = bq * 4;
  int i = s, j = s + w - 1;
  int wm1 = w - 1;
  int rr = t & 127, ks = t >> 7;

  if (t < wm1 * 4) {
    int k2 = t >> 2, bi = t & 3;
    sM[k2][bi] = bmax[((size_t)i * NN + (i + k2)) * BB + b0 + bi] +
                 bmax[((size_t)(i + k2 + 1) * NN + j) * BB + b0 + bi];
  }
  __syncthreads();
  if (t < 4) {
    float M = sM[0][t];
    for (int k2 = 1; k2 < wm1; k2++) M = fmaxf(M, sM[k2][t]);
    Mb4[t] = M;
  }
  // stage diagonal (ET) children once: rows f, stride PADR, only our 4 b's
  for (int f = t; f < CF; f += 512) {
    *(float4*)&ETL[f * PADR] = *(const float4*)&ET[((size_t)i * CF + f) * BB + b0];
    *(float4*)&ETR[f * PADR] = *(const float4*)&ET[((size_t)j * CF + f) * BB + b0];
  }

  float4 acc = {0.f, 0.f, 0.f, 0.f};
  const float4* rp = rules + (size_t)rr * CA;
  for (int kbase = 0; kbase < wm1; kbase += 4) {
    int nk = wm1 - kbase; if (nk > 4) nk = 4;
    // stage compact slices for this chunk (left child compact iff k>=1, right iff k<=wm1-2)
    int totrows = nk * CRP;
    for (int idx = t; idx < totrows; idx += 512) {
      int kk = idx / CRP; int f = idx - kk * CRP;
      int k = kbase + kk;
      if (k >= 1)
        *(float4*)&SLc[kk][f * PADR] = *(const float4*)&EB[(((size_t)i * NN + (i + k)) * CRP + f) * BB + b0];
      if (k <= wm1 - 2)
        *(float4*)&SRc[kk][f * PADR] = *(const float4*)&EB[(((size_t)(i + k + 1) * NN + j) * CRP + f) * BB + b0];
    }
    __syncthreads();
    int k = kbase + ks;
    if (k < wm1 && rr < CR) {
      bool ld = (k == 0), rd = (k == wm1 - 1);
      const float* Lb = ld ? ETL : SLc[ks];
      const float* Rb = rd ? ETR : SRc[ks];
      float4 kacc = {0.f, 0.f, 0.f, 0.f};
#pragma unroll 4
      for (int a = 0; a < CA; a++) {
        float4 rule = rp[a];
        int fL = __float_as_int(rule.z);
        int fR = __float_as_int(rule.w);
        int fLc = rd ? fL : min(fL, 120);
        int fRc = ld ? fR : min(fR, 120);
        float4 La = *(const float4*)&Lb[a * PADR];       // wave-uniform -> broadcast
        float4 Ra = *(const float4*)&Rb[a * PADR];
        float4 Rg = *(const float4*)&Rb[fLc * PADR];
        float4 Lg = *(const float4*)&Lb[fRc * PADR];
        kacc.x += rule.x * (La.x * Rg.x) + rule.y * (Lg.x * Ra.x);
        kacc.y += rule.x * (La.y * Rg.y) + rule.y * (Lg.y * Ra.y);
        kacc.z += rule.x * (La.z * Rg.z) + rule.y * (Lg.z * Ra.z);
        kacc.w += rule.x * (La.w * Rg.w) + rule.y * (Lg.w * Ra.w);
      }
      acc.x += kacc.x * __expf(sM[k][0] - Mb4[0]);
      acc.y += kacc.y * __expf(sM[k][1] - Mb4[1]);
      acc.z += kacc.z * __expf(sM[k][2] - Mb4[2]);
      acc.w += kacc.w * __expf(sM[k][3] - Mb4[3]);
    }
    __syncthreads();   // compact buffers reused next chunk
  }
  // reduce over the 4 k-subgroups
  sred[t] = acc;
  __syncthreads();
  if (ks == 0 && rr < CR) {
    for (int g = 1; g < 4; g++) {
      float4 o = sred[rr + g * 128];
      acc.x += o.x; acc.y += o.y; acc.z += o.z; acc.w += o.w;
    }
    sums[rr][0] = acc.x; sums[rr][1] = acc.y; sums[rr][2] = acc.z; sums[rr][3] = acc.w;
  }
  __syncthreads();
  if (t < 4) {
    float m = 0.f;
    for (int r2 = 0; r2 < CR; r2++) m = fmaxf(m, sums[r2][t]);
    m = fmaxf(m, 1e-35f);
    msum[t] = m;
    bmax[((size_t)i * NN + j) * BB + b0 + t] = Mb4[t] + __logf(m);
  }
  __syncthreads();
  if (ks == 0 && rr < CR) {
    float4 o;
    o.x = sums[rr][0] / msum[0]; o.y = sums[rr][1] / msum[1];
    o.z = sums[rr][2] / msum[2]; o.w = sums[rr][3] / msum[3];
    *(float4*)&EB[(((size_t)i * NN + j) * CRP + rr) * BB + b0] = o;
  }
  if (t < 4) EB[(((size_t)i * NN + j) * CRP + 120) * BB + b0 + t] = 0.f;
}

// ---------------- final (root folded in): out[b] = -(bmax + log sum_r e^{root_r} EB[r][b]) ----------------
__global__ __launch_bounds__(128) void k_final(const float* __restrict__ root_w,
                        const float* __restrict__ root_b, const float* __restrict__ root_mask,
                        const float* __restrict__ EB, const float* __restrict__ bmax,
                        float* __restrict__ out) {
  __shared__ float red[128];
  int b = blockIdx.x;
  int t = threadIdx.x;
  float xv[4];
  float lm = -INFINITY;
  for (int kq = 0; kq < 4; kq++) {
    int f = t + kq * 128;
    xv[kq] = (f < CF) ? (root_mask[f] + root_w[f] + root_b[f]) : -INFINITY;
    lm = fmaxf(lm, xv[kq]);
  }
  red[t] = lm; __syncthreads();
  for (int off = 64; off; off >>= 1) { if (t < off) red[t] = fmaxf(red[t], red[t + off]); __syncthreads(); }
  float M = red[0]; __syncthreads();
  float le = 0.f;
  for (int kq = 0; kq < 4; kq++) le += (t + kq * 128 < CF) ? __expf(xv[kq] - M) : 0.f;
  red[t] = le; __syncthreads();
  for (int off = 64; off; off >>= 1) { if (t < off) red[t] += red[t + off]; __syncthreads(); }
  float z = M + __logf(red[0]);
  __syncthreads();
  float x = (t < CR) ? __expf(xv[0] - z) * EB[(((size_t)0 * NN + (NN - 1)) * CRP + t) * BB + b] : 0.f;
  red[t] = x; __syncthreads();
  for (int off = 64; off; off >>= 1) { if (t < off) red[t] += red[t + off]; __syncthreads(); }
  if (t == 0) out[b] = -(bmax[(0 * NN + (NN - 1)) * BB + b] + __logf(red[0]));
}

extern "C" void kernel_launch(void* const* d_in, const int* in_sizes, int n_in,
                              void* d_out, int out_size, void* d_ws, size_t ws_size,
                              hipStream_t stream) {
  const float* nt_emb   = (const float*)d_in[1];
  const float* rule_W   = (const float*)d_in[2];
  const float* rule_b   = (const float*)d_in[3];
  const float* root_w   = (const float*)d_in[4];
  const float* root_b   = (const float*)d_in[5];
  const float* root_mask= (const float*)d_in[6];
  const float* split_W1 = (const float*)d_in[7];
  const float* split_b1 = (const float*)d_in[8];
  const float* res_W    = (const float*)d_in[9];
  const float* res_b    = (const float*)d_in[10];
  const float* split_Wo = (const float*)d_in[11];
  const float* split_bo = (const float*)d_in[12];
  const float* emit_W   = (const float*)d_in[13];
  const float* emit_b   = (const float*)d_in[14];
  const int*   words    = (const int*)d_in[15];
  const int*   lfunc    = (const int*)d_in[16];
  const int*   rfunc    = (const int*)d_in[17];

  float* ws = (float*)d_ws;
  float* ET           = ws;                          // 140800
  float* EB           = ET + NN * CF * BB;           // 937024
  float* bmaxbuf      = EB + NN * NN * CRP * BB;     // 7744
  float* rules        = bmaxbuf + NN * NN * BB;      // 23040
  float* split_scores = rules + CR * CA * 4;         // 800
  float* logZ         = split_scores + 2 * CF;       // 400
  float* partialE     = logZ + CF;                   // 12800

  hipLaunchKernelGGL(k_mlp, dim3(CF / 2), dim3(512), 0, stream, nt_emb, split_W1, split_b1,
                     res_W, res_b, split_Wo, split_bo, split_scores);
  hipLaunchKernelGGL(k_emit_partial, dim3(1200), dim3(128), 0, stream, nt_emb, emit_W, emit_b, partialE);
  hipLaunchKernelGGL(k_glgr, dim3(CR + 1), dim3(128), 0, stream, rule_W, rule_b, split_scores,
                     lfunc, rfunc, partialE, logZ, (float4*)rules);
  hipLaunchKernelGGL(k_term, dim3(BB * NN), dim3(512), 0, stream, nt_emb, emit_W, emit_b,
                     words, split_scores, logZ, ET, bmaxbuf);
  for (int w = 2; w <= NN; w++) {
    int S = NN - w + 1;
    hipLaunchKernelGGL(k_cky_w, dim3(S * 4), dim3(512), 0, stream,
                       (const float4*)rules, ET, EB, bmaxbuf, w);
  }
  hipLaunchKernelGGL(k_final, dim3(BB), dim3(128), 0, stream, root_w, root_b, root_mask,
                     EB, bmaxbuf, (float*)d_out);
}

// Round 11
// 370.355 us; speedup vs baseline: 6.0058x; 6.0058x over previous
//
#include <hip/hip_runtime.h>
#include <math.h>

#define D 256
#define V 10000
#define BB 16
#define NN 22
#define CF 400
#define CR 120
#define CA 48
#define CRP 121     // compact rows incl zero slot at 120
#define PADF 20     // LDS row pad (floats) -> 80B, cycles all 32 banks, 16B-aligned

// ---------------- MLP: 2 rows/block, 512 threads = 2 d-halves x 256 cols ----------------
__global__ __launch_bounds__(512) void k_mlp(const float* __restrict__ nt_emb, const float* __restrict__ W1,
                      const float* __restrict__ b1, const float* __restrict__ resW,
                      const float* __restrict__ resb, const float* __restrict__ Wo,
                      const float* __restrict__ bo, float* __restrict__ split_scores) {
  __shared__ float xs[2][D], hs[2][D], ts[2][D], prt[2][2][D];
  __shared__ float redg[2][4][2];
  int t = threadIdx.x; int c = t & 255; int h = t >> 8;
  int f0 = blockIdx.x * 2;
  xs[h][c] = nt_emb[(size_t)(f0 + h) * D + c];
  __syncthreads();
  int d0 = h * 128;
  float a0 = 0.f, a1 = 0.f;
#pragma unroll 8
  for (int dd = 0; dd < 128; dd++) {
    float wv = W1[(size_t)(d0 + dd) * D + c];
    a0 += xs[0][d0 + dd] * wv; a1 += xs[1][d0 + dd] * wv;
  }
  prt[0][h][c] = a0; prt[1][h][c] = a1;
  __syncthreads();
  if (h == 0) {
    float bv = b1[c];
    hs[0][c] = prt[0][0][c] + prt[0][1][c] + bv;
    hs[1][c] = prt[1][0][c] + prt[1][1][c] + bv;
  }
  __syncthreads();
  for (int il = 0; il < 2; il++) {
    const float* W = resW + (size_t)(il * 2) * D * D;
    a0 = 0.f; a1 = 0.f;
#pragma unroll 8
    for (int dd = 0; dd < 128; dd++) {
      float wv = W[(size_t)(d0 + dd) * D + c];
      a0 += hs[0][d0 + dd] * wv; a1 += hs[1][d0 + dd] * wv;
    }
    prt[0][h][c] = a0; prt[1][h][c] = a1;
    __syncthreads();
    if (h == 0) {
      float bv = resb[(il * 2) * D + c];
      ts[0][c] = fmaxf(prt[0][0][c] + prt[0][1][c] + bv, 0.f);
      ts[1][c] = fmaxf(prt[1][0][c] + prt[1][1][c] + bv, 0.f);
    }
    __syncthreads();
    const float* W2 = resW + (size_t)(il * 2 + 1) * D * D;
    a0 = 0.f; a1 = 0.f;
#pragma unroll 8
    for (int dd = 0; dd < 128; dd++) {
      float wv = W2[(size_t)(d0 + dd) * D + c];
      a0 += ts[0][d0 + dd] * wv; a1 += ts[1][d0 + dd] * wv;
    }
    prt[0][h][c] = a0; prt[1][h][c] = a1;
    __syncthreads();
    if (h == 0) {
      float bv = resb[(il * 2 + 1) * D + c];
      hs[0][c] = fmaxf(prt[0][0][c] + prt[0][1][c] + bv, 0.f) + hs[0][c];
      hs[1][c] = fmaxf(prt[1][0][c] + prt[1][1][c] + bv, 0.f) + hs[1][c];
    }
    __syncthreads();
  }
  float y0 = hs[h][c] * Wo[c * 2 + 0], y1 = hs[h][c] * Wo[c * 2 + 1];
  for (int off = 32; off; off >>= 1) { y0 += __shfl_down(y0, off, 64); y1 += __shfl_down(y1, off, 64); }
  int wq = (t >> 6) & 3;
  if ((t & 63) == 0) { redg[h][wq][0] = y0; redg[h][wq][1] = y1; }
  __syncthreads();
  if (c == 0) {
    float s0 = redg[h][0][0] + redg[h][1][0] + redg[h][2][0] + redg[h][3][0] + bo[0];
    float s1 = redg[h][0][1] + redg[h][1][1] + redg[h][2][1] + redg[h][3][1] + bo[1];
    float m = fmaxf(s0, s1);
    float z = m + __logf(__expf(s0 - m) + __expf(s1 - m));
    split_scores[(f0 + h) * 2 + 0] = s0 - z;
    split_scores[(f0 + h) * 2 + 1] = s1 - z;
  }
}

// ---------------- emission partition: 128 threads, 512-col tiles, RT=8 rows (round-6 verified) ----
#define RT 8
__global__ __launch_bounds__(128) void k_emit_partial(const float* __restrict__ nt_emb,
                               const float* __restrict__ emit_W,
                               const float* __restrict__ emit_b, float* __restrict__ partial) {
  __shared__ float xs[RT][D];
  __shared__ float ldsw[RT][2];
  int t = threadIdx.x;
  int f0 = blockIdx.x * RT;
  int v0 = blockIdx.y * 512 + t * 4;
  for (int idx = t; idx < RT * D; idx += 128) {
    int ri = idx >> 8, d = idx & 255;
    xs[ri][d] = nt_emb[(size_t)(f0 + ri) * D + d];
  }
  __syncthreads();
  float psum[RT];
  for (int ri = 0; ri < RT; ri++) psum[ri] = 0.f;
  if (v0 < V) {
    float acc[RT][4];
#pragma unroll
    for (int ri = 0; ri < RT; ri++)
      for (int j = 0; j < 4; j++) acc[ri][j] = 0.f;
    for (int d4 = 0; d4 < D / 4; d4++) {
      float4 w0 = *(const float4*)(emit_W + (size_t)(4 * d4 + 0) * V + v0);
      float4 w1 = *(const float4*)(emit_W + (size_t)(4 * d4 + 1) * V + v0);
      float4 w2 = *(const float4*)(emit_W + (size_t)(4 * d4 + 2) * V + v0);
      float4 w3 = *(const float4*)(emit_W + (size_t)(4 * d4 + 3) * V + v0);
#pragma unroll
      for (int ri = 0; ri < RT; ri++) {
        float4 xv = *(const float4*)(&xs[ri][4 * d4]);
        acc[ri][0] += xv.x * w0.x + xv.y * w1.x + xv.z * w2.x + xv.w * w3.x;
        acc[ri][1] += xv.x * w0.y + xv.y * w1.y + xv.z * w2.y + xv.w * w3.y;
        acc[ri][2] += xv.x * w0.z + xv.y * w1.z + xv.z * w2.z + xv.w * w3.z;
        acc[ri][3] += xv.x * w0.w + xv.y * w1.w + xv.z * w2.w + xv.w * w3.w;
      }
    }
    float4 eb = *(const float4*)(emit_b + v0);
#pragma unroll
    for (int ri = 0; ri < RT; ri++)
      psum[ri] = __expf(acc[ri][0] + eb.x) + __expf(acc[ri][1] + eb.y) +
                 __expf(acc[ri][2] + eb.z) + __expf(acc[ri][3] + eb.w);
  }
  int lane = t & 63, wid = t >> 6;
  for (int ri = 0; ri < RT; ri++) {
    float v = psum[ri];
    for (int off = 32; off; off >>= 1) v += __shfl_down(v, off, 64);
    if (lane == 0) ldsw[ri][wid] = v;
  }
  __syncthreads();
  if (t < RT) partial[(f0 + t) * 32 + blockIdx.y] = ldsw[t][0] + ldsw[t][1];
}

// ---------------- rules pack + logZ (block CR does logZ) ----------------
__global__ void k_glgr(const float* __restrict__ rule_W, const float* __restrict__ rule_b,
                       const float* __restrict__ split_scores,
                       const int* __restrict__ lf, const int* __restrict__ rf,
                       const float* __restrict__ partialE, float* __restrict__ logZ,
                       float4* __restrict__ rules) {
  __shared__ float red[128];
  __shared__ float shv[96];
  int r = blockIdx.x;
  int t = threadIdx.x;
  if (r == CR) {
    for (int f = t; f < CF; f += 128) {
      float s = 0.f;
      for (int ct = 0; ct < 20; ct++) s += partialE[f * 32 + ct];
      logZ[f] = __logf(s);
    }
    return;
  }
  float x = (t < 96) ? (rule_W[t * CR + r] + rule_b[t]) : -INFINITY;
  red[t] = x; __syncthreads();
  for (int off = 64; off; off >>= 1) { if (t < off) red[t] = fmaxf(red[t], red[t + off]); __syncthreads(); }
  float m = red[0]; __syncthreads();
  red[t] = (t < 96) ? __expf(x - m) : 0.f; __syncthreads();
  for (int off = 64; off; off >>= 1) { if (t < off) red[t] += red[t + off]; __syncthreads(); }
  float z = m + __logf(red[0]);
  float s0 = split_scores[r * 2 + 0];
  if (t < 96) shv[t] = __expf((x - z) + s0);
  __syncthreads();
  if (t < CA) {
    float4 pk;
    pk.x = shv[t];
    pk.y = shv[CA + t];
    pk.z = __int_as_float(rf[r * CA + t]);
    pk.w = __int_as_float(lf[r * CA + t]);
    rules[r * CA + t] = pk;
  }
}

// ---------------- terminal: ET[n][f][b] = exp(term - bmax), bmax to table ----------------
__global__ __launch_bounds__(512) void k_term(const float* __restrict__ nt_emb,
                       const float* __restrict__ emit_W,
                       const float* __restrict__ emit_b, const int* __restrict__ words,
                       const float* __restrict__ split_scores, const float* __restrict__ logZ,
                       float* __restrict__ ET, float* __restrict__ bmax) {
  __shared__ float vals[CF];
  __shared__ float redw[8];
  __shared__ float mfin;
  int blk = blockIdx.x;
  int b = blk / NN, n = blk % NN;
  int t = threadIdx.x;
  int lane = t & 63, wid = t >> 6;
  int wd = words[b * NN + n];
  float wc0 = emit_W[(size_t)(4 * lane + 0) * V + wd];
  float wc1 = emit_W[(size_t)(4 * lane + 1) * V + wd];
  float wc2 = emit_W[(size_t)(4 * lane + 2) * V + wd];
  float wc3 = emit_W[(size_t)(4 * lane + 3) * V + wd];
  float eb = emit_b[wd];
  float vmax = -INFINITY;
  int fbase = wid * 50;
  for (int k = 0; k < 50; k += 2) {
    int f0 = fbase + k, f1 = f0 + 1;
    float4 xa = *(const float4*)(nt_emb + (size_t)f0 * D + 4 * lane);
    float4 xb = *(const float4*)(nt_emb + (size_t)f1 * D + 4 * lane);
    float va = xa.x * wc0 + xa.y * wc1 + xa.z * wc2 + xa.w * wc3;
    float vb = xb.x * wc0 + xb.y * wc1 + xb.z * wc2 + xb.w * wc3;
    for (int off = 32; off; off >>= 1) {
      va += __shfl_down(va, off, 64);
      vb += __shfl_down(vb, off, 64);
    }
    if (lane == 0) {
      float fa = split_scores[f0 * 2 + 1] + (va + eb) - logZ[f0];
      float fb = split_scores[f1 * 2 + 1] + (vb + eb) - logZ[f1];
      vals[f0] = fa; vals[f1] = fb;
      vmax = fmaxf(vmax, fmaxf(fa, fb));
    }
  }
  if (lane == 0) redw[wid] = vmax;
  __syncthreads();
  if (t == 0) {
    float m = redw[0];
    for (int i2 = 1; i2 < 8; i2++) m = fmaxf(m, redw[i2]);
    mfin = m;
    bmax[(n * NN + n) * BB + b] = m;
  }
  __syncthreads();
  float m = mfin;
  for (int f = t; f < CF; f += 512) ET[((size_t)n * CF + f) * BB + b] = __expf(vals[f] - m);
}

// ---------------- CKY partial: block = (s, k, r-chunk), all 16 b, float4 over b ----------------
__global__ __launch_bounds__(512) void k_cky_part(const float4* __restrict__ rules,
                      const float* __restrict__ ET, const float* __restrict__ EB,
                      const float* __restrict__ bmax, float* __restrict__ partial,
                      int w, int rsplit) {
  __shared__ float SL[CF * PADF];
  __shared__ float SR[CF * PADF];
  __shared__ float sMbuf[21 * BB];
  __shared__ float cks[BB];
  __shared__ float4 sred[512];
  int t = threadIdx.x;
  int blk = blockIdx.x;
  int rb = blk % rsplit; int rem = blk / rsplit;
  int wm1 = w - 1;
  int k = rem % wm1; int s = rem / wm1;
  int i = s, j = s + w - 1;
  bool ld = (k == 0), rd = (k == wm1 - 1);
  if (t < BB * wm1) {
    int k2 = t >> 4, b2 = t & 15;
    sMbuf[t] = bmax[(i * NN + (i + k2)) * BB + b2] + bmax[((i + k2 + 1) * NN + j) * BB + b2];
  }
  __syncthreads();
  if (t < BB) {
    float M = sMbuf[t];
    for (int k2 = 1; k2 < wm1; k2++) M = fmaxf(M, sMbuf[k2 * BB + t]);
    cks[t] = __expf(sMbuf[k * BB + t] - M);
  }
  const float* srcL = ld ? (ET + (size_t)i * CF * BB) : (EB + (size_t)(i * NN + (i + k)) * CRP * BB);
  const float* srcR = rd ? (ET + (size_t)j * CF * BB) : (EB + (size_t)((i + k + 1) * NN + j) * CRP * BB);
  int rowsL = ld ? CF : CRP, rowsR = rd ? CF : CRP;
  for (int idx = t; idx < rowsL * 4; idx += 512) {
    int f = idx >> 2, q = idx & 3;
    *(float4*)&SL[f * PADF + q * 4] = *(const float4*)&srcL[f * BB + q * 4];
  }
  for (int idx = t; idx < rowsR * 4; idx += 512) {
    int f = idx >> 2, q = idx & 3;
    *(float4*)&SR[f * PADF + q * 4] = *(const float4*)&srcR[f * BB + q * 4];
  }
  __syncthreads();
  int nr = CR / rsplit;        // 120, 60, 30
  int asplit = 128 / nr;       // 1, 2, 4
  int bq = t & 3, rr = t >> 2; // rr < 128
  float4 acc = {0.f, 0.f, 0.f, 0.f};
  bool act = (rr < nr * asplit);
  int rloc = rr % nr, asub = rr / nr;
  int r = rb * nr + rloc;
  if (act) {
    int na = CA / asplit;
    const float4* rp = rules + (size_t)r * CA + asub * na;
    int boff = bq * 4;
    int aB = asub * na;
#pragma unroll 4
    for (int a0 = 0; a0 < na; a0++) {
      float4 rule = rp[a0];
      int a = aB + a0;
      int fL = __float_as_int(rule.z);
      int fR = __float_as_int(rule.w);
      int fLc = rd ? fL : min(fL, 120);
      int fRc = ld ? fR : min(fR, 120);
      float4 La = *(const float4*)&SL[a * PADF + boff];
      float4 Ra = *(const float4*)&SR[a * PADF + boff];
      float4 Rg = *(const float4*)&SR[fLc * PADF + boff];
      float4 Lg = *(const float4*)&SL[fRc * PADF + boff];
      acc.x += rule.x * (La.x * Rg.x) + rule.y * (Lg.x * Ra.x);
      acc.y += rule.x * (La.y * Rg.y) + rule.y * (Lg.y * Ra.y);
      acc.z += rule.x * (La.z * Rg.z) + rule.y * (Lg.z * Ra.z);
      acc.w += rule.x * (La.w * Rg.w) + rule.y * (Lg.w * Ra.w);
    }
  }
  if (asplit > 1) {
    sred[t] = acc;
    __syncthreads();
    if (act && asub == 0) {
      for (int s2 = 1; s2 < asplit; s2++) {
        float4 o = sred[t + s2 * nr * 4];
        acc.x += o.x; acc.y += o.y; acc.z += o.z; acc.w += o.w;
      }
    }
  }
  if (act && asub == 0) {
    float4 c4 = *(const float4*)&cks[bq * 4];
    acc.x *= c4.x; acc.y *= c4.y; acc.z *= c4.z; acc.w *= c4.w;
    *(float4*)&partial[(((size_t)s * 21 + k) * CR + r) * BB + bq * 4] = acc;
  }
}

// ---------------- CKY combine: sum k-partials, renormalize to EB + bmax ----------------
__global__ __launch_bounds__(512) void k_cky_comb(const float* __restrict__ partial,
                      float* __restrict__ EB, float* __restrict__ bmax, int w) {
  __shared__ float sums[CR * BB];
  __shared__ float sMbuf[21 * BB];
  __shared__ float msum[BB];
  __shared__ float Mb[BB];
  int t = threadIdx.x;
  int s = blockIdx.x;
  int i = s, j = s + w - 1;
  int wm1 = w - 1;
  if (t < BB * wm1) {
    int k2 = t >> 4, b2 = t & 15;
    sMbuf[t] = bmax[(i * NN + (i + k2)) * BB + b2] + bmax[((i + k2 + 1) * NN + j) * BB + b2];
  }
  __syncthreads();
  if (t < BB) {
    float M = sMbuf[t];
    for (int k2 = 1; k2 < wm1; k2++) M = fmaxf(M, sMbuf[k2 * BB + t]);
    Mb[t] = M;
  }
  int bq = t & 3, rr = t >> 2;
  float4 sum = {0.f, 0.f, 0.f, 0.f};
  if (rr < CR) {
    for (int k2 = 0; k2 < wm1; k2++) {
      float4 p = *(const float4*)&partial[(((size_t)s * 21 + k2) * CR + rr) * BB + bq * 4];
      sum.x += p.x; sum.y += p.y; sum.z += p.z; sum.w += p.w;
    }
    *(float4*)&sums[rr * BB + bq * 4] = sum;
  }
  __syncthreads();
  if (t < BB) {
    float m = 0.f;
    for (int r2 = 0; r2 < CR; r2++) m = fmaxf(m, sums[r2 * BB + t]);
    m = fmaxf(m, 1e-35f);
    msum[t] = m;
    bmax[(i * NN + j) * BB + t] = Mb[t] + __logf(m);
  }
  __syncthreads();
  if (rr < CR) {
    float4 m4 = *(const float4*)&msum[bq * 4];
    sum.x /= m4.x; sum.y /= m4.y; sum.z /= m4.z; sum.w /= m4.w;
    *(float4*)&EB[(((size_t)i * NN + j) * CRP + rr) * BB + bq * 4] = sum;
  }
  if (t < BB) EB[(((size_t)i * NN + j) * CRP + 120) * BB + t] = 0.f;
}

// ---------------- final (root folded in): out[b] = -(bmax + log sum_r e^{root_r} EB[r][b]) ----------------
__global__ __launch_bounds__(128) void k_final(const float* __restrict__ root_w,
                        const float* __restrict__ root_b, const float* __restrict__ root_mask,
                        const float* __restrict__ EB, const float* __restrict__ bmax,
                        float* __restrict__ out) {
  __shared__ float red[128];
  int b = blockIdx.x;
  int t = threadIdx.x;
  float xv[4];
  float lm = -INFINITY;
  for (int kq = 0; kq < 4; kq++) {
    int f = t + kq * 128;
    xv[kq] = (f < CF) ? (root_mask[f] + root_w[f] + root_b[f]) : -INFINITY;
    lm = fmaxf(lm, xv[kq]);
  }
  red[t] = lm; __syncthreads();
  for (int off = 64; off; off >>= 1) { if (t < off) red[t] = fmaxf(red[t], red[t + off]); __syncthreads(); }
  float M = red[0]; __syncthreads();
  float le = 0.f;
  for (int kq = 0; kq < 4; kq++) le += (t + kq * 128 < CF) ? __expf(xv[kq] - M) : 0.f;
  red[t] = le; __syncthreads();
  for (int off = 64; off; off >>= 1) { if (t < off) red[t] += red[t + off]; __syncthreads(); }
  float z = M + __logf(red[0]);
  __syncthreads();
  float x = (t < CR) ? __expf(xv[0] - z) * EB[(((size_t)0 * NN + (NN - 1)) * CRP + t) * BB + b] : 0.f;
  red[t] = x; __syncthreads();
  for (int off = 64; off; off >>= 1) { if (t < off) red[t] += red[t + off]; __syncthreads(); }
  if (t == 0) out[b] = -(bmax[(0 * NN + (NN - 1)) * BB + b] + __logf(red[0]));
}

extern "C" void kernel_launch(void* const* d_in, const int* in_sizes, int n_in,
                              void* d_out, int out_size, void* d_ws, size_t ws_size,
                              hipStream_t stream) {
  const float* nt_emb   = (const float*)d_in[1];
  const float* rule_W   = (const float*)d_in[2];
  const float* rule_b   = (const float*)d_in[3];
  const float* root_w   = (const float*)d_in[4];
  const float* root_b   = (const float*)d_in[5];
  const float* root_mask= (const float*)d_in[6];
  const float* split_W1 = (const float*)d_in[7];
  const float* split_b1 = (const float*)d_in[8];
  const float* res_W    = (const float*)d_in[9];
  const float* res_b    = (const float*)d_in[10];
  const float* split_Wo = (const float*)d_in[11];
  const float* split_bo = (const float*)d_in[12];
  const float* emit_W   = (const float*)d_in[13];
  const float* emit_b   = (const float*)d_in[14];
  const int*   words    = (const int*)d_in[15];
  const int*   lfunc    = (const int*)d_in[16];
  const int*   rfunc    = (const int*)d_in[17];

  float* ws = (float*)d_ws;
  float* ET           = ws;                          // 140800
  float* EB           = ET + NN * CF * BB;           // 937024
  float* bmaxbuf      = EB + NN * NN * CRP * BB;     // 7744
  float* partialK     = bmaxbuf + NN * NN * BB;      // 846720
  float* rules        = partialK + 21 * 21 * CR * BB;// 23040
  float* split_scores = rules + CR * CA * 4;         // 800
  float* logZ         = split_scores + 2 * CF;       // 400
  float* partialE     = logZ + CF;                   // 12800

  hipLaunchKernelGGL(k_mlp, dim3(CF / 2), dim3(512), 0, stream, nt_emb, split_W1, split_b1,
                     res_W, res_b, split_Wo, split_bo, split_scores);
  hipLaunchKernelGGL(k_emit_partial, dim3(CF / RT, 20), dim3(128), 0, stream, nt_emb, emit_W, emit_b, partialE);
  hipLaunchKernelGGL(k_glgr, dim3(CR + 1), dim3(128), 0, stream, rule_W, rule_b, split_scores,
                     lfunc, rfunc, partialE, logZ, (float4*)rules);
  hipLaunchKernelGGL(k_term, dim3(BB * NN), dim3(512), 0, stream, nt_emb, emit_W, emit_b,
                     words, split_scores, logZ, ET, bmaxbuf);
  for (int w = 2; w <= NN; w++) {
    int S = NN - w + 1;
    int units = S * (w - 1);
    int rsplit = (units >= 224) ? 1 : ((units >= 112) ? 2 : 4);
    hipLaunchKernelGGL(k_cky_part, dim3(units * rsplit), dim3(512), 0, stream,
                       (const float4*)rules, ET, EB, bmaxbuf, partialK, w, rsplit);
    hipLaunchKernelGGL(k_cky_comb, dim3(S), dim3(512), 0, stream, partialK, EB, bmaxbuf, w);
  }
  hipLaunchKernelGGL(k_final, dim3(BB), dim3(128), 0, stream, root_w, root_b, root_mask,
                     EB, bmaxbuf, (float*)d_out);
}

// Round 12
// 349.299 us; speedup vs baseline: 6.3678x; 1.0603x over previous
//
#include <hip/hip_runtime.h>
#include <math.h>

#define D 256
#define V 10000
#define BB 16
#define NN 22
#define CF 400
#define CR 120
#define CA 48
#define CRP 121     // compact rows incl zero slot at 120
#define PADF 20     // LDS row pad (floats) -> 80B, cycles all 32 banks, 16B-aligned

// ---------------- FUSED: blocks 0..199 = MLP (2 rows each); blocks 200..449 = emit partition ----
// Emit: RT=8 rows x 2048-col tile, 512 threads, 4 cols/thread. 50 row-groups x 5 col-tiles.
#define RT 8
#define MLPB 200
__global__ __launch_bounds__(512) void k_mlp_emit(const float* __restrict__ nt_emb,
                      const float* __restrict__ W1, const float* __restrict__ b1,
                      const float* __restrict__ resW, const float* __restrict__ resb,
                      const float* __restrict__ Wo, const float* __restrict__ bo,
                      const float* __restrict__ emit_W, const float* __restrict__ emit_b,
                      float* __restrict__ split_scores, float* __restrict__ partial) {
  int bid = blockIdx.x;
  int t = threadIdx.x;
  if (bid < MLPB) {
    // ================= MLP path (round-11 verified body) =================
    __shared__ float xs[2][D], hs[2][D], ts[2][D], prt[2][2][D];
    __shared__ float redg[2][4][2];
    int c = t & 255; int h = t >> 8;
    int f0 = bid * 2;
    xs[h][c] = nt_emb[(size_t)(f0 + h) * D + c];
    __syncthreads();
    int d0 = h * 128;
    float a0 = 0.f, a1 = 0.f;
#pragma unroll 8
    for (int dd = 0; dd < 128; dd++) {
      float wv = W1[(size_t)(d0 + dd) * D + c];
      a0 += xs[0][d0 + dd] * wv; a1 += xs[1][d0 + dd] * wv;
    }
    prt[0][h][c] = a0; prt[1][h][c] = a1;
    __syncthreads();
    if (h == 0) {
      float bv = b1[c];
      hs[0][c] = prt[0][0][c] + prt[0][1][c] + bv;
      hs[1][c] = prt[1][0][c] + prt[1][1][c] + bv;
    }
    __syncthreads();
    for (int il = 0; il < 2; il++) {
      const float* W = resW + (size_t)(il * 2) * D * D;
      a0 = 0.f; a1 = 0.f;
#pragma unroll 8
      for (int dd = 0; dd < 128; dd++) {
        float wv = W[(size_t)(d0 + dd) * D + c];
        a0 += hs[0][d0 + dd] * wv; a1 += hs[1][d0 + dd] * wv;
      }
      prt[0][h][c] = a0; prt[1][h][c] = a1;
      __syncthreads();
      if (h == 0) {
        float bv = resb[(il * 2) * D + c];
        ts[0][c] = fmaxf(prt[0][0][c] + prt[0][1][c] + bv, 0.f);
        ts[1][c] = fmaxf(prt[1][0][c] + prt[1][1][c] + bv, 0.f);
      }
      __syncthreads();
      const float* W2 = resW + (size_t)(il * 2 + 1) * D * D;
      a0 = 0.f; a1 = 0.f;
#pragma unroll 8
      for (int dd = 0; dd < 128; dd++) {
        float wv = W2[(size_t)(d0 + dd) * D + c];
        a0 += ts[0][d0 + dd] * wv; a1 += ts[1][d0 + dd] * wv;
      }
      prt[0][h][c] = a0; prt[1][h][c] = a1;
      __syncthreads();
      if (h == 0) {
        float bv = resb[(il * 2 + 1) * D + c];
        hs[0][c] = fmaxf(prt[0][0][c] + prt[0][1][c] + bv, 0.f) + hs[0][c];
        hs[1][c] = fmaxf(prt[1][0][c] + prt[1][1][c] + bv, 0.f) + hs[1][c];
      }
      __syncthreads();
    }
    float y0 = hs[h][c] * Wo[c * 2 + 0], y1 = hs[h][c] * Wo[c * 2 + 1];
    for (int off = 32; off; off >>= 1) { y0 += __shfl_down(y0, off, 64); y1 += __shfl_down(y1, off, 64); }
    int wq = (t >> 6) & 3;
    if ((t & 63) == 0) { redg[h][wq][0] = y0; redg[h][wq][1] = y1; }
    __syncthreads();
    if (c == 0) {
      float s0 = redg[h][0][0] + redg[h][1][0] + redg[h][2][0] + redg[h][3][0] + bo[0];
      float s1 = redg[h][0][1] + redg[h][1][1] + redg[h][2][1] + redg[h][3][1] + bo[1];
      float m = fmaxf(s0, s1);
      float z = m + __logf(__expf(s0 - m) + __expf(s1 - m));
      split_scores[(f0 + h) * 2 + 0] = s0 - z;
      split_scores[(f0 + h) * 2 + 1] = s1 - z;
    }
  } else {
    // ================= emit path =================
    __shared__ float exs[RT][D];
    __shared__ float ldsw[RT][8];
    int e = bid - MLPB;          // 0..249
    int y = e / 50;              // col tile 0..4 (2048 cols each)
    int xt = e % 50;             // row group
    int f0 = xt * RT;
    int v0 = y * 2048 + t * 4;
    for (int idx = t; idx < RT * D; idx += 512) {
      int ri = idx >> 8, d = idx & 255;
      exs[ri][d] = nt_emb[(size_t)(f0 + ri) * D + d];
    }
    __syncthreads();
    float psum[RT];
    for (int ri = 0; ri < RT; ri++) psum[ri] = 0.f;
    if (v0 < V) {                // tile 4 spans 8192..10239; threads past 10000 idle
      float acc[RT][4];
#pragma unroll
      for (int ri = 0; ri < RT; ri++)
        for (int j = 0; j < 4; j++) acc[ri][j] = 0.f;
      for (int d4 = 0; d4 < D / 4; d4++) {
        float4 w0 = *(const float4*)(emit_W + (size_t)(4 * d4 + 0) * V + v0);
        float4 w1 = *(const float4*)(emit_W + (size_t)(4 * d4 + 1) * V + v0);
        float4 w2 = *(const float4*)(emit_W + (size_t)(4 * d4 + 2) * V + v0);
        float4 w3 = *(const float4*)(emit_W + (size_t)(4 * d4 + 3) * V + v0);
#pragma unroll
        for (int ri = 0; ri < RT; ri++) {
          float4 xv = *(const float4*)(&exs[ri][4 * d4]);
          acc[ri][0] += xv.x * w0.x + xv.y * w1.x + xv.z * w2.x + xv.w * w3.x;
          acc[ri][1] += xv.x * w0.y + xv.y * w1.y + xv.z * w2.y + xv.w * w3.y;
          acc[ri][2] += xv.x * w0.z + xv.y * w1.z + xv.z * w2.z + xv.w * w3.z;
          acc[ri][3] += xv.x * w0.w + xv.y * w1.w + xv.z * w2.w + xv.w * w3.w;
        }
      }
      float4 eb = *(const float4*)(emit_b + v0);
#pragma unroll
      for (int ri = 0; ri < RT; ri++)
        psum[ri] = __expf(acc[ri][0] + eb.x) + __expf(acc[ri][1] + eb.y) +
                   __expf(acc[ri][2] + eb.z) + __expf(acc[ri][3] + eb.w);
    }
    int lane = t & 63, wid = t >> 6;
    for (int ri = 0; ri < RT; ri++) {
      float v = psum[ri];
      for (int off = 32; off; off >>= 1) v += __shfl_down(v, off, 64);
      if (lane == 0) ldsw[ri][wid] = v;
    }
    __syncthreads();
    if (t < RT) {
      float s = 0.f;
      for (int wv = 0; wv < 8; wv++) s += ldsw[t][wv];
      partial[(f0 + t) * 8 + y] = s;
    }
  }
}

// ---------------- rules pack + logZ (block CR does logZ) ----------------
__global__ void k_glgr(const float* __restrict__ rule_W, const float* __restrict__ rule_b,
                       const float* __restrict__ split_scores,
                       const int* __restrict__ lf, const int* __restrict__ rf,
                       const float* __restrict__ partialE, float* __restrict__ logZ,
                       float4* __restrict__ rules) {
  __shared__ float red[128];
  __shared__ float shv[96];
  int r = blockIdx.x;
  int t = threadIdx.x;
  if (r == CR) {
    for (int f = t; f < CF; f += 128) {
      float s = 0.f;
      for (int ct = 0; ct < 5; ct++) s += partialE[f * 8 + ct];
      logZ[f] = __logf(s);
    }
    return;
  }
  float x = (t < 96) ? (rule_W[t * CR + r] + rule_b[t]) : -INFINITY;
  red[t] = x; __syncthreads();
  for (int off = 64; off; off >>= 1) { if (t < off) red[t] = fmaxf(red[t], red[t + off]); __syncthreads(); }
  float m = red[0]; __syncthreads();
  red[t] = (t < 96) ? __expf(x - m) : 0.f; __syncthreads();
  for (int off = 64; off; off >>= 1) { if (t < off) red[t] += red[t + off]; __syncthreads(); }
  float z = m + __logf(red[0]);
  float s0 = split_scores[r * 2 + 0];
  if (t < 96) shv[t] = __expf((x - z) + s0);
  __syncthreads();
  if (t < CA) {
    float4 pk;
    pk.x = shv[t];
    pk.y = shv[CA + t];
    pk.z = __int_as_float(rf[r * CA + t]);
    pk.w = __int_as_float(lf[r * CA + t]);
    rules[r * CA + t] = pk;
  }
}

// ---------------- terminal: ET[n][f][b] = exp(term - bmax), bmax to table ----------------
__global__ __launch_bounds__(512) void k_term(const float* __restrict__ nt_emb,
                       const float* __restrict__ emit_W,
                       const float* __restrict__ emit_b, const int* __restrict__ words,
                       const float* __restrict__ split_scores, const float* __restrict__ logZ,
                       float* __restrict__ ET, float* __restrict__ bmax) {
  __shared__ float vals[CF];
  __shared__ float redw[8];
  __shared__ float mfin;
  int blk = blockIdx.x;
  int b = blk / NN, n = blk % NN;
  int t = threadIdx.x;
  int lane = t & 63, wid = t >> 6;
  int wd = words[b * NN + n];
  float wc0 = emit_W[(size_t)(4 * lane + 0) * V + wd];
  float wc1 = emit_W[(size_t)(4 * lane + 1) * V + wd];
  float wc2 = emit_W[(size_t)(4 * lane + 2) * V + wd];
  float wc3 = emit_W[(size_t)(4 * lane + 3) * V + wd];
  float eb = emit_b[wd];
  float vmax = -INFINITY;
  int fbase = wid * 50;
  for (int k = 0; k < 50; k += 2) {
    int f0 = fbase + k, f1 = f0 + 1;
    float4 xa = *(const float4*)(nt_emb + (size_t)f0 * D + 4 * lane);
    float4 xb = *(const float4*)(nt_emb + (size_t)f1 * D + 4 * lane);
    float va = xa.x * wc0 + xa.y * wc1 + xa.z * wc2 + xa.w * wc3;
    float vb = xb.x * wc0 + xb.y * wc1 + xb.z * wc2 + xb.w * wc3;
    for (int off = 32; off; off >>= 1) {
      va += __shfl_down(va, off, 64);
      vb += __shfl_down(vb, off, 64);
    }
    if (lane == 0) {
      float fa = split_scores[f0 * 2 + 1] + (va + eb) - logZ[f0];
      float fb = split_scores[f1 * 2 + 1] + (vb + eb) - logZ[f1];
      vals[f0] = fa; vals[f1] = fb;
      vmax = fmaxf(vmax, fmaxf(fa, fb));
    }
  }
  if (lane == 0) redw[wid] = vmax;
  __syncthreads();
  if (t == 0) {
    float m = redw[0];
    for (int i2 = 1; i2 < 8; i2++) m = fmaxf(m, redw[i2]);
    mfin = m;
    bmax[(n * NN + n) * BB + b] = m;
  }
  __syncthreads();
  float m = mfin;
  for (int f = t; f < CF; f += 512) ET[((size_t)n * CF + f) * BB + b] = __expf(vals[f] - m);
}

// ---------------- CKY partial: block = (s, k, r-chunk), all 16 b, float4 over b ----------------
__global__ __launch_bounds__(512) void k_cky_part(const float4* __restrict__ rules,
                      const float* __restrict__ ET, const float* __restrict__ EB,
                      const float* __restrict__ bmax, float* __restrict__ partial,
                      int w, int rsplit) {
  __shared__ float SL[CF * PADF];
  __shared__ float SR[CF * PADF];
  __shared__ float sMbuf[21 * BB];
  __shared__ float cks[BB];
  __shared__ float4 sred[512];
  int t = threadIdx.x;
  int blk = blockIdx.x;
  int rb = blk % rsplit; int rem = blk / rsplit;
  int wm1 = w - 1;
  int k = rem % wm1; int s = rem / wm1;
  int i = s, j = s + w - 1;
  bool ld = (k == 0), rd = (k == wm1 - 1);
  if (t < BB * wm1) {
    int k2 = t >> 4, b2 = t & 15;
    sMbuf[t] = bmax[(i * NN + (i + k2)) * BB + b2] + bmax[((i + k2 + 1) * NN + j) * BB + b2];
  }
  __syncthreads();
  if (t < BB) {
    float M = sMbuf[t];
    for (int k2 = 1; k2 < wm1; k2++) M = fmaxf(M, sMbuf[k2 * BB + t]);
    cks[t] = __expf(sMbuf[k * BB + t] - M);
  }
  const float* srcL = ld ? (ET + (size_t)i * CF * BB) : (EB + (size_t)(i * NN + (i + k)) * CRP * BB);
  const float* srcR = rd ? (ET + (size_t)j * CF * BB) : (EB + (size_t)((i + k + 1) * NN + j) * CRP * BB);
  int rowsL = ld ? CF : CRP, rowsR = rd ? CF : CRP;
  for (int idx = t; idx < rowsL * 4; idx += 512) {
    int f = idx >> 2, q = idx & 3;
    *(float4*)&SL[f * PADF + q * 4] = *(const float4*)&srcL[f * BB + q * 4];
  }
  for (int idx = t; idx < rowsR * 4; idx += 512) {
    int f = idx >> 2, q = idx & 3;
    *(float4*)&SR[f * PADF + q * 4] = *(const float4*)&srcR[f * BB + q * 4];
  }
  __syncthreads();
  int nr = CR / rsplit;        // 120, 60, 30, 15
  int asplit = 128 / nr;       // 1, 2, 4, 8
  int bq = t & 3, rr = t >> 2; // rr < 128
  float4 acc = {0.f, 0.f, 0.f, 0.f};
  bool act = (rr < nr * asplit);
  int rloc = rr % nr, asub = rr / nr;
  int r = rb * nr + rloc;
  if (act) {
    int na = CA / asplit;
    const float4* rp = rules + (size_t)r * CA + asub * na;
    int boff = bq * 4;
    int aB = asub * na;
#pragma unroll 4
    for (int a0 = 0; a0 < na; a0++) {
      float4 rule = rp[a0];
      int a = aB + a0;
      int fL = __float_as_int(rule.z);
      int fR = __float_as_int(rule.w);
      int fLc = rd ? fL : min(fL, 120);
      int fRc = ld ? fR : min(fR, 120);
      float4 La = *(const float4*)&SL[a * PADF + boff];
      float4 Ra = *(const float4*)&SR[a * PADF + boff];
      float4 Rg = *(const float4*)&SR[fLc * PADF + boff];
      float4 Lg = *(const float4*)&SL[fRc * PADF + boff];
      acc.x += rule.x * (La.x * Rg.x) + rule.y * (Lg.x * Ra.x);
      acc.y += rule.x * (La.y * Rg.y) + rule.y * (Lg.y * Ra.y);
      acc.z += rule.x * (La.z * Rg.z) + rule.y * (Lg.z * Ra.z);
      acc.w += rule.x * (La.w * Rg.w) + rule.y * (Lg.w * Ra.w);
    }
  }
  if (asplit > 1) {
    sred[t] = acc;
    __syncthreads();
    if (act && asub == 0) {
      for (int s2 = 1; s2 < asplit; s2++) {
        float4 o = sred[t + s2 * nr * 4];
        acc.x += o.x; acc.y += o.y; acc.z += o.z; acc.w += o.w;
      }
    }
  }
  if (act && asub == 0) {
    float4 c4 = *(const float4*)&cks[bq * 4];
    acc.x *= c4.x; acc.y *= c4.y; acc.z *= c4.z; acc.w *= c4.w;
    *(float4*)&partial[(((size_t)s * 21 + k) * CR + r) * BB + bq * 4] = acc;
  }
}

// ---------------- CKY combine: sum k-partials, renormalize to EB + bmax ----------------
__global__ __launch_bounds__(512) void k_cky_comb(const float* __restrict__ partial,
                      float* __restrict__ EB, float* __restrict__ bmax, int w) {
  __shared__ float sums[CR * BB];
  __shared__ float sMbuf[21 * BB];
  __shared__ float msum[BB];
  __shared__ float Mb[BB];
  int t = threadIdx.x;
  int s = blockIdx.x;
  int i = s, j = s + w - 1;
  int wm1 = w - 1;
  if (t < BB * wm1) {
    int k2 = t >> 4, b2 = t & 15;
    sMbuf[t] = bmax[(i * NN + (i + k2)) * BB + b2] + bmax[((i + k2 + 1) * NN + j) * BB + b2];
  }
  __syncthreads();
  if (t < BB) {
    float M = sMbuf[t];
    for (int k2 = 1; k2 < wm1; k2++) M = fmaxf(M, sMbuf[k2 * BB + t]);
    Mb[t] = M;
  }
  int bq = t & 3, rr = t >> 2;
  float4 sum = {0.f, 0.f, 0.f, 0.f};
  if (rr < CR) {
    for (int k2 = 0; k2 < wm1; k2++) {
      float4 p = *(const float4*)&partial[(((size_t)s * 21 + k2) * CR + rr) * BB + bq * 4];
      sum.x += p.x; sum.y += p.y; sum.z += p.z; sum.w += p.w;
    }
    *(float4*)&sums[rr * BB + bq * 4] = sum;
  }
  __syncthreads();
  if (t < BB) {
    float m = 0.f;
    for (int r2 = 0; r2 < CR; r2++) m = fmaxf(m, sums[r2 * BB + t]);
    m = fmaxf(m, 1e-35f);
    msum[t] = m;
    bmax[(i * NN + j) * BB + t] = Mb[t] + __logf(m);
  }
  __syncthreads();
  if (rr < CR) {
    float4 m4 = *(const float4*)&msum[bq * 4];
    sum.x /= m4.x; sum.y /= m4.y; sum.z /= m4.z; sum.w /= m4.w;
    *(float4*)&EB[(((size_t)i * NN + j) * CRP + rr) * BB + bq * 4] = sum;
  }
  if (t < BB) EB[(((size_t)i * NN + j) * CRP + 120) * BB + t] = 0.f;
}

// ---------------- final (root folded in): out[b] = -(bmax + log sum_r e^{root_r} EB[r][b]) ----------------
__global__ __launch_bounds__(128) void k_final(const float* __restrict__ root_w,
                        const float* __restrict__ root_b, const float* __restrict__ root_mask,
                        const float* __restrict__ EB, const float* __restrict__ bmax,
                        float* __restrict__ out) {
  __shared__ float red[128];
  int b = blockIdx.x;
  int t = threadIdx.x;
  float xv[4];
  float lm = -INFINITY;
  for (int kq = 0; kq < 4; kq++) {
    int f = t + kq * 128;
    xv[kq] = (f < CF) ? (root_mask[f] + root_w[f] + root_b[f]) : -INFINITY;
    lm = fmaxf(lm, xv[kq]);
  }
  red[t] = lm; __syncthreads();
  for (int off = 64; off; off >>= 1) { if (t < off) red[t] = fmaxf(red[t], red[t + off]); __syncthreads(); }
  float M = red[0]; __syncthreads();
  float le = 0.f;
  for (int kq = 0; kq < 4; kq++) le += (t + kq * 128 < CF) ? __expf(xv[kq] - M) : 0.f;
  red[t] = le; __syncthreads();
  for (int off = 64; off; off >>= 1) { if (t < off) red[t] += red[t + off]; __syncthreads(); }
  float z = M + __logf(red[0]);
  __syncthreads();
  float x = (t < CR) ? __expf(xv[0] - z) * EB[(((size_t)0 * NN + (NN - 1)) * CRP + t) * BB + b] : 0.f;
  red[t] = x; __syncthreads();
  for (int off = 64; off; off >>= 1) { if (t < off) red[t] += red[t + off]; __syncthreads(); }
  if (t == 0) out[b] = -(bmax[(0 * NN + (NN - 1)) * BB + b] + __logf(red[0]));
}

extern "C" void kernel_launch(void* const* d_in, const int* in_sizes, int n_in,
                              void* d_out, int out_size, void* d_ws, size_t ws_size,
                              hipStream_t stream) {
  const float* nt_emb   = (const float*)d_in[1];
  const float* rule_W   = (const float*)d_in[2];
  const float* rule_b   = (const float*)d_in[3];
  const float* root_w   = (const float*)d_in[4];
  const float* root_b   = (const float*)d_in[5];
  const float* root_mask= (const float*)d_in[6];
  const float* split_W1 = (const float*)d_in[7];
  const float* split_b1 = (const float*)d_in[8];
  const float* res_W    = (const float*)d_in[9];
  const float* res_b    = (const float*)d_in[10];
  const float* split_Wo = (const float*)d_in[11];
  const float* split_bo = (const float*)d_in[12];
  const float* emit_W   = (const float*)d_in[13];
  const float* emit_b   = (const float*)d_in[14];
  const int*   words    = (const int*)d_in[15];
  const int*   lfunc    = (const int*)d_in[16];
  const int*   rfunc    = (const int*)d_in[17];

  float* ws = (float*)d_ws;
  float* ET           = ws;                          // 140800
  float* EB           = ET + NN * CF * BB;           // 937024
  float* bmaxbuf      = EB + NN * NN * CRP * BB;     // 7744
  float* partialK     = bmaxbuf + NN * NN * BB;      // 846720
  float* rules        = partialK + 21 * 21 * CR * BB;// 23040
  float* split_scores = rules + CR * CA * 4;         // 800
  float* logZ         = split_scores + 2 * CF;       // 400
  float* partialE     = logZ + CF;                   // 3200

  hipLaunchKernelGGL(k_mlp_emit, dim3(MLPB + 250), dim3(512), 0, stream, nt_emb,
                     split_W1, split_b1, res_W, res_b, split_Wo, split_bo,
                     emit_W, emit_b, split_scores, partialE);
  hipLaunchKernelGGL(k_glgr, dim3(CR + 1), dim3(128), 0, stream, rule_W, rule_b, split_scores,
                     lfunc, rfunc, partialE, logZ, (float4*)rules);
  hipLaunchKernelGGL(k_term, dim3(BB * NN), dim3(512), 0, stream, nt_emb, emit_W, emit_b,
                     words, split_scores, logZ, ET, bmaxbuf);
  for (int w = 2; w <= NN; w++) {
    int S = NN - w + 1;
    int units = S * (w - 1);
    int rsplit = (units >= 224) ? 1 : ((units >= 112) ? 2 : ((units >= 56) ? 4 : 8));
    hipLaunchKernelGGL(k_cky_part, dim3(units * rsplit), dim3(512), 0, stream,
                       (const float4*)rules, ET, EB, bmaxbuf, partialK, w, rsplit);
    hipLaunchKernelGGL(k_cky_comb, dim3(S), dim3(512), 0, stream, partialK, EB, bmaxbuf, w);
  }
  hipLaunchKernelGGL(k_final, dim3(BB), dim3(128), 0, stream, root_w, root_b, root_mask,
                     EB, bmaxbuf, (float*)d_out);
}